// Round 15
// baseline (94.788 us; speedup 1.0000x reference)
//
#include <hip/hip_runtime.h>
#include <hip/hip_bf16.h>

// Problem constants
#define BB 96    // batch
#define HH 100   // history length
#define NN 128   // candidates (broadcast only)
#define DD 768   // embed dim
#define AA 256   // attention dim

#define WSLAB 196608   // 768*256, one MT partial slab (floats)

static __device__ __forceinline__ float dot4(float4 a, float4 b) {
  return a.x * b.x + a.y * b.y + a.z * b.z + a.w * b.w;
}

// ---------------------------------------------------------------------------
// D1 k_prep (1152 blocks):
//   [0,768)     : MTp[s][d,a] = sum_{e in slab s} WK[a,e]*Wr[e,d]
//                 split-K-4: 192 tiles (32x32) x 4 slabs -> 6 K-tiles/block.
//   [768,1152)  : neigh partials, 4 h-groups x 96 b (24 h each)
// ---------------------------------------------------------------------------
__global__ void __launch_bounds__(256)
k_prep(const float* __restrict__ Wr, const float* __restrict__ WK,
       const float* __restrict__ hist,
       float* __restrict__ MTp, float* __restrict__ neighp) {
  int bid = blockIdx.x, tid = threadIdx.x;
  if (bid < 768) {
    __shared__ float sL[32][33];  // [a][e] tile (reused as transpose stage)
    __shared__ float sR[32][33];  // [e][d] tile
    int s = bid / 192;            // K-slab (e in [s*192, s*192+192))
    int t = bid % 192;
    int d0 = (t % 24) * 32, a0 = (t / 24) * 32;
    int tx = tid & 31, ty = tid >> 5;  // 32 x 8
    float acc[4] = {0.f, 0.f, 0.f, 0.f};
    int ebase = s * 192;
    for (int e0 = ebase; e0 < ebase + 192; e0 += 32) {  // 6 K-tiles
#pragma unroll
      for (int k = 0; k < 4; ++k) {
        sL[ty + 8 * k][tx] = WK[(size_t)(a0 + ty + 8 * k) * DD + e0 + tx];
        sR[ty + 8 * k][tx] = Wr[(size_t)(e0 + ty + 8 * k) * DD + d0 + tx];
      }
      __syncthreads();
#pragma unroll 8
      for (int e = 0; e < 32; ++e) {
        float w = sR[e][tx];
#pragma unroll
        for (int k = 0; k < 4; ++k) acc[k] += sL[ty + 8 * k][e] * w;
      }
      __syncthreads();
    }
    // transpose stage -> coalesced d-major writes of MT[d][a]
#pragma unroll
    for (int k = 0; k < 4; ++k) sL[ty + 8 * k][tx] = acc[k];
    __syncthreads();
    float* MTs = MTp + (size_t)s * WSLAB;
#pragma unroll
    for (int k = 0; k < 4; ++k)
      MTs[(size_t)(d0 + ty + 8 * k) * AA + a0 + tx] = sL[tx][ty + 8 * k];
  } else {
    int id = bid - 768;
    int b = id % BB, hg = id / BB;  // 4 h-groups of 24
    if (tid < 192) {
      const float* hb = hist + (size_t)b * HH * DD + (size_t)hg * 24 * DD + tid * 4;
      float4 a0 = make_float4(0.f, 0.f, 0.f, 0.f);
      float4 a1 = make_float4(0.f, 0.f, 0.f, 0.f);
#pragma unroll
      for (int h = 0; h < 24; h += 2) {
        float4 x = *(const float4*)(hb + (size_t)h * DD);
        float4 y = *(const float4*)(hb + (size_t)(h + 1) * DD);
        a0.x += x.x; a0.y += x.y; a0.z += x.z; a0.w += x.w;
        a1.x += y.x; a1.y += y.y; a1.z += y.z; a1.w += y.w;
      }
      float4 m = make_float4(a0.x + a1.x, a0.y + a1.y, a0.z + a1.z, a0.w + a1.w);
      *(float4*)(neighp + ((size_t)hg * BB + b) * DD + tid * 4) = m;
    }
  }
}

// ---------------------------------------------------------------------------
// D2 k_mid (1368 blocks) — all independent gen-2 work in one dispatch:
//   [0,576)     : G[d2,d1] = sum_a MT[d2,a]*WQ[a,d1]   (K=256, 8 K-tiles;
//                 MT read as sum of 4 MTp slabs, L2-resident)
//   [576,1344)  : nl[b,e] = neigh·W_l[e]+b_l ; u0[b,e] = hist0·W_r[e]+nl
//                 (neigh = (1/96)*sum of 4 neighp slabs, inline)
//   [1344,1368) : cv[d] = sum_a MT[d,a]*bQ[a]
// ---------------------------------------------------------------------------
__global__ void __launch_bounds__(256)
k_mid(const float* __restrict__ MTp, const float* __restrict__ WQ,
      const float* __restrict__ bQ, const float* __restrict__ neighp,
      const float* __restrict__ hist, const float* __restrict__ Wl,
      const float* __restrict__ bl, const float* __restrict__ Wr,
      float* __restrict__ G, float* __restrict__ nl, float* __restrict__ u0,
      float* __restrict__ cv) {
  int bid = blockIdx.x, tid = threadIdx.x;
  if (bid < 576) {
    __shared__ float sA[32][33];  // MT tile [d2_local][a_local]
    __shared__ float sB[32][33];  // WQ tile [a_local][d1_local]
    int d1_0 = (bid % 24) * 32, d2_0 = (bid / 24) * 32;
    int tx = tid & 31, ty = tid >> 5;  // 32 x 8
    float acc[4] = {0.f, 0.f, 0.f, 0.f};
    for (int a0 = 0; a0 < AA; a0 += 32) {  // 8 K-tiles
#pragma unroll
      for (int k = 0; k < 4; ++k) {
        size_t rMT = (size_t)(d2_0 + ty + 8 * k) * AA + a0 + tx;
        sA[ty + 8 * k][tx] = MTp[rMT] + MTp[WSLAB + rMT] +
                             MTp[2 * WSLAB + rMT] + MTp[3 * WSLAB + rMT];
        sB[ty + 8 * k][tx] = WQ[(size_t)(a0 + ty + 8 * k) * DD + d1_0 + tx];
      }
      __syncthreads();
#pragma unroll 8
      for (int a = 0; a < 32; ++a) {
        float wb = sB[a][tx];
#pragma unroll
        for (int k = 0; k < 4; ++k) acc[k] += sA[ty + 8 * k][a] * wb;
      }
      __syncthreads();
    }
#pragma unroll
    for (int k = 0; k < 4; ++k)   // G[d2][d1], coalesced over tx
      G[(size_t)(d2_0 + ty + 8 * k) * DD + d1_0 + tx] = acc[k];
  } else if (bid < 1344) {
    int id = bid - 576;
    int e0 = (id % 24) * 32;
    int b0 = (id / 24) * 3;
    int lane = tid & 63, wave = tid >> 6;
    float4 xn[3][3], xh[3][3];
#pragma unroll
    for (int bi = 0; bi < 3; ++bi) {
      int b = b0 + bi;
#pragma unroll
      for (int jj = 0; jj < 3; ++jj) {
        int idx = lane + 64 * jj;
        float4 s = make_float4(0.f, 0.f, 0.f, 0.f);
#pragma unroll
        for (int g = 0; g < 4; ++g) {
          float4 x = ((const float4*)(neighp + ((size_t)g * BB + b) * DD))[idx];
          s.x += x.x; s.y += x.y; s.z += x.z; s.w += x.w;
        }
        xn[bi][jj] = make_float4(s.x * (1.f / 96.f), s.y * (1.f / 96.f),
                                 s.z * (1.f / 96.f), s.w * (1.f / 96.f));
        xh[bi][jj] = ((const float4*)(hist + (size_t)b * HH * DD))[idx];  // h=0
      }
    }
    for (int i = 0; i < 8; ++i) {
      int e = e0 + wave * 8 + i;
      const float4* wl4 = (const float4*)(Wl + (size_t)e * DD);
      const float4* wr4 = (const float4*)(Wr + (size_t)e * DD);
      float pl[3] = {0.f, 0.f, 0.f}, pr[3] = {0.f, 0.f, 0.f};
#pragma unroll
      for (int jj = 0; jj < 3; ++jj) {
        float4 wl = wl4[lane + 64 * jj];
        float4 wr = wr4[lane + 64 * jj];
#pragma unroll
        for (int bi = 0; bi < 3; ++bi) {
          pl[bi] += dot4(wl, xn[bi][jj]);
          pr[bi] += dot4(wr, xh[bi][jj]);
        }
      }
#pragma unroll
      for (int bi = 0; bi < 3; ++bi) {
        float pp = pl[bi], qq = pr[bi];
        for (int off = 32; off; off >>= 1) {
          pp += __shfl_down(pp, off, 64);
          qq += __shfl_down(qq, off, 64);
        }
        if (lane == 0) {
          float nle = pp + bl[e];
          nl[(size_t)(b0 + bi) * DD + e] = nle;
          u0[(size_t)(b0 + bi) * DD + e] = qq + nle;
        }
      }
    }
  } else {
    // cv[d] = MT[d,:]·bQ  (24 blocks x 32 d, wave-split over K=256)
    int d0 = (bid - 1344) * 32;
    int lane = tid & 63, wave = tid >> 6;
    float4 x = ((const float4*)bQ)[lane];  // 256 floats = 64 float4
    for (int i = 0; i < 8; ++i) {
      int d = d0 + wave * 8 + i;
      size_t r4 = ((size_t)d * AA) / 4 + lane;
      const float4* p0 = (const float4*)MTp;
      float4 w0 = p0[r4];
      float4 w1 = p0[WSLAB / 4 + r4];
      float4 w2 = p0[2 * (WSLAB / 4) + r4];
      float4 w3 = p0[3 * (WSLAB / 4) + r4];
      float4 w = make_float4(w0.x + w1.x + w2.x + w3.x, w0.y + w1.y + w2.y + w3.y,
                             w0.z + w1.z + w2.z + w3.z, w0.w + w1.w + w2.w + w3.w);
      float p = dot4(w, x);
      for (int off = 32; off; off >>= 1) p += __shfl_down(p, off, 64);
      if (lane == 0) cv[d] = p;
    }
  }
}

// ---------------------------------------------------------------------------
// D3 k_v: v[b,d] = (G[d,:]·u0[b,:] + cv[d]) / 16   grid (24, 32), K = 768
// ---------------------------------------------------------------------------
__global__ void k_v(const float* __restrict__ u0, const float* __restrict__ G,
                    const float* __restrict__ cv, float* __restrict__ vv) {
  int d0 = blockIdx.x * 32;
  int b0 = blockIdx.y * 3;
  int lane = threadIdx.x & 63, wave = threadIdx.x >> 6;
  float4 x[3][3];
#pragma unroll
  for (int bi = 0; bi < 3; ++bi)
#pragma unroll
    for (int jj = 0; jj < 3; ++jj)
      x[bi][jj] = ((const float4*)(u0 + (size_t)(b0 + bi) * DD))[lane + 64 * jj];
  for (int i = 0; i < 8; ++i) {
    int d = d0 + wave * 8 + i;
    const float4* g4 = (const float4*)(G + (size_t)d * DD);
    float p[3] = {0.f, 0.f, 0.f};
#pragma unroll
    for (int jj = 0; jj < 3; ++jj) {
      float4 w = g4[lane + 64 * jj];
#pragma unroll
      for (int bi = 0; bi < 3; ++bi) p[bi] += dot4(w, x[bi][jj]);
    }
#pragma unroll
    for (int bi = 0; bi < 3; ++bi) {
      float pp = p[bi];
      for (int off = 32; off; off >>= 1) pp += __shfl_down(pp, off, 64);
      if (lane == 0)
        vv[(size_t)(b0 + bi) * DD + d] = (pp + cv[d]) * (1.f / 16.f);
    }
  }
}

// ---------------------------------------------------------------------------
// D4 k_scores: scores[b,h] = hist[b,h,:]·v[b,:]   grid (96, 5), 20 h/block
// ---------------------------------------------------------------------------
__global__ void k_scores(const float* __restrict__ hist, const float* __restrict__ vv,
                         float* __restrict__ sc) {
  int b = blockIdx.x, hg = blockIdx.y;
  int lane = threadIdx.x & 63, wave = threadIdx.x >> 6;
  float4 v[3];
  const float4* vb = (const float4*)(vv + (size_t)b * DD);
#pragma unroll
  for (int jj = 0; jj < 3; ++jj) v[jj] = vb[lane + 64 * jj];
  const float* hb = hist + (size_t)b * HH * DD;
  for (int i = 0; i < 5; ++i) {
    int h = hg * 20 + wave * 5 + i;
    const float4* r = (const float4*)(hb + (size_t)h * DD);
    float p = 0.f;
#pragma unroll
    for (int jj = 0; jj < 3; ++jj) p += dot4(r[lane + 64 * jj], v[jj]);
    for (int off = 32; off; off >>= 1) p += __shfl_down(p, off, 64);
    if (lane == 0) sc[b * 128 + h] = p;
  }
}

// ---------------------------------------------------------------------------
// D5 k_wsum: softmax (wave 0, per block) + weighted hist sum.
// HIGH-TLP: grid (96, 12), 64 e/block, 4 h-groups x 25 h/thread, LDS reduce.
// ---------------------------------------------------------------------------
__global__ void __launch_bounds__(256)
k_wsum(const float* __restrict__ hist, const float* __restrict__ sc,
       float* __restrict__ wsum) {
  int b = blockIdx.x;
  int es = blockIdx.y;                 // 64-col slice
  int tid = threadIdx.x, lane = tid & 63, wave = tid >> 6;
  __shared__ float sal[HH];
  __shared__ float psum[4][64];
  if (tid < HH) sal[tid] = sc[b * 128 + tid];
  __syncthreads();
  if (wave == 0) {
    float x0 = (lane < HH) ? sal[lane] : -1e30f;
    float x1 = (lane + 64 < HH) ? sal[lane + 64] : -1e30f;
    float m = fmaxf(x0, x1);
    for (int off = 32; off; off >>= 1) m = fmaxf(m, __shfl_xor(m, off, 64));
    float e0 = (lane < HH) ? __expf(x0 - m) : 0.f;
    float e1 = (lane + 64 < HH) ? __expf(x1 - m) : 0.f;
    float s = e0 + e1;
    for (int off = 32; off; off >>= 1) s += __shfl_xor(s, off, 64);
    float inv = 1.f / s;
    if (lane < HH) sal[lane] = e0 * inv;
    if (lane + 64 < HH) sal[lane + 64] = e1 * inv;
  }
  __syncthreads();
  int e = es * 64 + lane;
  const float* hb = hist + (size_t)b * HH * DD + e;
  int h0 = wave * 25;
  float acc = 0.f;
#pragma unroll
  for (int i = 0; i < 25; i += 5) {  // 5 loads in flight per batch
    float v0 = hb[(size_t)(h0 + i + 0) * DD];
    float v1 = hb[(size_t)(h0 + i + 1) * DD];
    float v2 = hb[(size_t)(h0 + i + 2) * DD];
    float v3 = hb[(size_t)(h0 + i + 3) * DD];
    float v4 = hb[(size_t)(h0 + i + 4) * DD];
    acc += sal[h0 + i + 0] * v0 + sal[h0 + i + 1] * v1 + sal[h0 + i + 2] * v2 +
           sal[h0 + i + 3] * v3 + sal[h0 + i + 4] * v4;
  }
  psum[wave][lane] = acc;
  __syncthreads();
  if (tid < 64) {
    float s = psum[0][tid] + psum[1][tid] + psum[2][tid] + psum[3][tid];
    wsum[(size_t)b * DD + es * 64 + tid] = s;
  }
}

// ---------------------------------------------------------------------------
// D6 k_orow_write: orow[b,d] = nl[b,d] + wsum[b,:]·W_r[d,:], then broadcast
// directly to out[b, 0..127, d] (via LDS stage). grid (24, 32).
// ---------------------------------------------------------------------------
__global__ void k_orow_write(const float* __restrict__ wsum, const float* __restrict__ Wr,
                             const float* __restrict__ nl, float* __restrict__ out) {
  int d0 = blockIdx.x * 32;
  int b0 = blockIdx.y * 3;
  int lane = threadIdx.x & 63, wave = threadIdx.x >> 6;
  __shared__ __align__(16) float s_o[3][32];
  float4 x[3][3];
#pragma unroll
  for (int bi = 0; bi < 3; ++bi)
#pragma unroll
    for (int jj = 0; jj < 3; ++jj)
      x[bi][jj] = ((const float4*)(wsum + (size_t)(b0 + bi) * DD))[lane + 64 * jj];
  for (int i = 0; i < 8; ++i) {
    int d = d0 + wave * 8 + i;
    const float4* w4 = (const float4*)(Wr + (size_t)d * DD);
    float p[3] = {0.f, 0.f, 0.f};
#pragma unroll
    for (int jj = 0; jj < 3; ++jj) {
      float4 w = w4[lane + 64 * jj];
#pragma unroll
      for (int bi = 0; bi < 3; ++bi) p[bi] += dot4(w, x[bi][jj]);
    }
#pragma unroll
    for (int bi = 0; bi < 3; ++bi) {
      float pp = p[bi];
      for (int off = 32; off; off >>= 1) pp += __shfl_down(pp, off, 64);
      if (lane == 0)
        s_o[bi][wave * 8 + i] = pp + nl[(size_t)(b0 + bi) * DD + d];
    }
  }
  __syncthreads();
  float4* out4 = (float4*)out;
  int d4 = d0 >> 2;
#pragma unroll
  for (int k = 0; k < 12; ++k) {
    int g = threadIdx.x + (k << 8);
    int seg = g >> 3, off = g & 7;
    int bi = seg >> 7, n = seg & 127;
    float4 val = *(const float4*)&s_o[bi][off * 4];
    out4[((size_t)(b0 + bi) * NN + n) * (DD / 4) + d4 + off] = val;
  }
}

// ---------------------------------------------------------------------------
extern "C" void kernel_launch(void* const* d_in, const int* in_sizes, int n_in,
                              void* d_out, int out_size, void* d_ws, size_t ws_size,
                              hipStream_t stream) {
  const float *hist = nullptr, *Wl = nullptr, *Wr = nullptr, *WK = nullptr,
              *WQ = nullptr, *bl = nullptr, *bQ = nullptr;
  int seenDxD = 0, seenAxD = 0;
  for (int i = 0; i < n_in; ++i) {
    int s = in_sizes[i];
    const float* p = (const float*)d_in[i];
    if (s == BB * HH * DD) hist = p;
    else if (s == BB * NN * DD) { /* candidate — unused */ }
    else if (s == DD * DD) { if (seenDxD++ == 0) Wl = p; else Wr = p; }
    else if (s == AA * DD) { if (seenAxD++ == 0) WK = p; else WQ = p; }
    else if (s == DD) bl = p;
    else if (s == AA) bQ = p;
  }

  float* ws = (float*)d_ws;
  float* MTp    = ws + 0;         // 4 * 196608 = 786432
  float* G      = ws + 786432;    // 589824
  float* neighp = ws + 1376256;   // 4*96*768 = 294912
  float* nl     = ws + 1671168;   // 73728
  float* u0     = ws + 1744896;   // 73728
  float* cv     = ws + 1818624;   // 768 (pad to 1024)
  float* vv     = ws + 1819648;   // 73728
  float* sc     = ws + 1893376;   // 12288
  float* wsum   = ws + 1905664;   // 73728  -> total ~7.9 MB
  float* out = (float*)d_out;

  k_prep      <<<dim3(1152),   dim3(256), 0, stream>>>(Wr, WK, hist, MTp, neighp);
  k_mid       <<<dim3(1368),   dim3(256), 0, stream>>>(MTp, WQ, bQ, neighp, hist,
                                                       Wl, bl, Wr, G, nl, u0, cv);
  k_v         <<<dim3(24, 32), dim3(256), 0, stream>>>(u0, G, cv, vv);
  k_scores    <<<dim3(96, 5),  dim3(256), 0, stream>>>(hist, vv, sc);
  k_wsum      <<<dim3(96, 12), dim3(256), 0, stream>>>(hist, sc, wsum);
  k_orow_write<<<dim3(24, 32), dim3(256), 0, stream>>>(wsum, Wr, nl, out);
}

// Round 16
// 87.467 us; speedup vs baseline: 1.0837x; 1.0837x over previous
//
#include <hip/hip_runtime.h>
#include <hip/hip_bf16.h>

// Problem constants
#define BB 96    // batch
#define HH 100   // history length
#define NN 128   // candidates (broadcast only)
#define DD 768   // embed dim
#define AA 256   // attention dim

#define WSLAB 196608   // 768*256, one MT partial slab (floats)
#define WSLAB4 49152   // in float4

static __device__ __forceinline__ float dot4(float4 a, float4 b) {
  return a.x * b.x + a.y * b.y + a.z * b.z + a.w * b.w;
}

// ---------------------------------------------------------------------------
// D1 k_prep (1152 blocks):
//   [0,768)     : MTp[s][d,a] = sum_{e in slab s} WK[a,e]*Wr[e,d]
//                 split-K-4: 192 tiles (32x32) x 4 slabs -> 6 K-tiles/block.
//   [768,1152)  : neigh partials, 4 h-groups x 96 b (24 h each)
// ---------------------------------------------------------------------------
__global__ void __launch_bounds__(256)
k_prep(const float* __restrict__ Wr, const float* __restrict__ WK,
       const float* __restrict__ hist,
       float* __restrict__ MTp, float* __restrict__ neighp) {
  int bid = blockIdx.x, tid = threadIdx.x;
  if (bid < 768) {
    __shared__ float sL[32][33];  // [a][e] tile (reused as transpose stage)
    __shared__ float sR[32][33];  // [e][d] tile
    int s = bid / 192;            // K-slab (e in [s*192, s*192+192))
    int t = bid % 192;
    int d0 = (t % 24) * 32, a0 = (t / 24) * 32;
    int tx = tid & 31, ty = tid >> 5;  // 32 x 8
    float acc[4] = {0.f, 0.f, 0.f, 0.f};
    int ebase = s * 192;
    for (int e0 = ebase; e0 < ebase + 192; e0 += 32) {  // 6 K-tiles
#pragma unroll
      for (int k = 0; k < 4; ++k) {
        sL[ty + 8 * k][tx] = WK[(size_t)(a0 + ty + 8 * k) * DD + e0 + tx];
        sR[ty + 8 * k][tx] = Wr[(size_t)(e0 + ty + 8 * k) * DD + d0 + tx];
      }
      __syncthreads();
#pragma unroll 8
      for (int e = 0; e < 32; ++e) {
        float w = sR[e][tx];
#pragma unroll
        for (int k = 0; k < 4; ++k) acc[k] += sL[ty + 8 * k][e] * w;
      }
      __syncthreads();
    }
    // transpose stage -> coalesced d-major writes
#pragma unroll
    for (int k = 0; k < 4; ++k) sL[ty + 8 * k][tx] = acc[k];
    __syncthreads();
    float* MTs = MTp + (size_t)s * WSLAB;
#pragma unroll
    for (int k = 0; k < 4; ++k)
      MTs[(size_t)(d0 + ty + 8 * k) * AA + a0 + tx] = sL[tx][ty + 8 * k];
  } else {
    int id = bid - 768;
    int b = id % BB, hg = id / BB;  // 4 h-groups of 24
    if (tid < 192) {
      const float* hb = hist + (size_t)b * HH * DD + (size_t)hg * 24 * DD + tid * 4;
      float4 a0 = make_float4(0.f, 0.f, 0.f, 0.f);
      float4 a1 = make_float4(0.f, 0.f, 0.f, 0.f);
#pragma unroll
      for (int h = 0; h < 24; h += 2) {
        float4 x = *(const float4*)(hb + (size_t)h * DD);
        float4 y = *(const float4*)(hb + (size_t)(h + 1) * DD);
        a0.x += x.x; a0.y += x.y; a0.z += x.z; a0.w += x.w;
        a1.x += y.x; a1.y += y.y; a1.z += y.z; a1.w += y.w;
      }
      float4 m = make_float4(a0.x + a1.x, a0.y + a1.y, a0.z + a1.z, a0.w + a1.w);
      *(float4*)(neighp + ((size_t)hg * BB + b) * DD + tid * 4) = m;
    }
  }
}

// ---------------------------------------------------------------------------
// D2 k_nl_u0: nl[b,e] = neigh[b,:]·W_l[e,:] + b_l[e];
//             u0[b,e] = hist[b,0,:]·W_r[e,:] + nl[b,e]
// neigh = (1/96) * sum of 4 neighp slabs (inline). grid (24, 32)
// ---------------------------------------------------------------------------
__global__ void k_nl_u0(const float* __restrict__ neighp, const float* __restrict__ hist,
                        const float* __restrict__ Wl, const float* __restrict__ bl,
                        const float* __restrict__ Wr,
                        float* __restrict__ nl, float* __restrict__ u0) {
  int e0 = blockIdx.x * 32;
  int b0 = blockIdx.y * 3;
  int lane = threadIdx.x & 63, wave = threadIdx.x >> 6;
  float4 xn[3][3], xh[3][3];
#pragma unroll
  for (int bi = 0; bi < 3; ++bi) {
    int b = b0 + bi;
#pragma unroll
    for (int jj = 0; jj < 3; ++jj) {
      int idx = lane + 64 * jj;
      float4 s = make_float4(0.f, 0.f, 0.f, 0.f);
#pragma unroll
      for (int g = 0; g < 4; ++g) {
        float4 x = ((const float4*)(neighp + ((size_t)g * BB + b) * DD))[idx];
        s.x += x.x; s.y += x.y; s.z += x.z; s.w += x.w;
      }
      xn[bi][jj] = make_float4(s.x * (1.f / 96.f), s.y * (1.f / 96.f),
                               s.z * (1.f / 96.f), s.w * (1.f / 96.f));
      xh[bi][jj] = ((const float4*)(hist + (size_t)b * HH * DD))[idx];  // h=0 row
    }
  }
  for (int i = 0; i < 8; ++i) {
    int e = e0 + wave * 8 + i;
    const float4* wl4 = (const float4*)(Wl + (size_t)e * DD);
    const float4* wr4 = (const float4*)(Wr + (size_t)e * DD);
    float pl[3] = {0.f, 0.f, 0.f}, pr[3] = {0.f, 0.f, 0.f};
#pragma unroll
    for (int jj = 0; jj < 3; ++jj) {
      float4 wl = wl4[lane + 64 * jj];
      float4 wr = wr4[lane + 64 * jj];
#pragma unroll
      for (int bi = 0; bi < 3; ++bi) {
        pl[bi] += dot4(wl, xn[bi][jj]);
        pr[bi] += dot4(wr, xh[bi][jj]);
      }
    }
#pragma unroll
    for (int bi = 0; bi < 3; ++bi) {
      float pp = pl[bi], qq = pr[bi];
      for (int off = 32; off; off >>= 1) {
        pp += __shfl_down(pp, off, 64);
        qq += __shfl_down(qq, off, 64);
      }
      if (lane == 0) {
        float nle = pp + bl[e];
        nl[(size_t)(b0 + bi) * DD + e] = nle;
        u0[(size_t)(b0 + bi) * DD + e] = qq + nle;
      }
    }
  }
}

// ---------------------------------------------------------------------------
// D3 k_q (448 blocks flat):
//   [0,256)   : Q[b,a] = u0[b,:]·W_Q[a,:] + b_Q[a]
//   [256,448) : MT = MTp[0]+MTp[1]+MTp[2]+MTp[3]  (float4 elementwise)
// ---------------------------------------------------------------------------
__global__ void __launch_bounds__(256)
k_q(const float* __restrict__ u0, const float* __restrict__ WQ,
    const float* __restrict__ bQ, const float* __restrict__ MTp,
    float* __restrict__ Qm, float* __restrict__ MT) {
  int bid = blockIdx.x, tid = threadIdx.x;
  if (bid < 256) {
    int a0 = (bid & 7) * 32;
    int b0 = (bid >> 3) * 3;
    int lane = tid & 63, wave = tid >> 6;
    float4 x[3][3];
#pragma unroll
    for (int bi = 0; bi < 3; ++bi)
#pragma unroll
      for (int jj = 0; jj < 3; ++jj)
        x[bi][jj] = ((const float4*)(u0 + (size_t)(b0 + bi) * DD))[lane + 64 * jj];
    for (int i = 0; i < 8; ++i) {
      int a = a0 + wave * 8 + i;
      const float4* w4 = (const float4*)(WQ + (size_t)a * DD);
      float p[3] = {0.f, 0.f, 0.f};
#pragma unroll
      for (int jj = 0; jj < 3; ++jj) {
        float4 w = w4[lane + 64 * jj];
#pragma unroll
        for (int bi = 0; bi < 3; ++bi) p[bi] += dot4(w, x[bi][jj]);
      }
#pragma unroll
      for (int bi = 0; bi < 3; ++bi) {
        float pp = p[bi];
        for (int off = 32; off; off >>= 1) pp += __shfl_down(pp, off, 64);
        if (lane == 0) Qm[(size_t)(b0 + bi) * AA + a] = pp + bQ[a];
      }
    }
  } else {
    int i4 = (bid - 256) * 256 + tid;  // float4 index, 192*256 = 49152 total
    const float4* p = (const float4*)MTp;
    float4 a = p[i4], b = p[WSLAB4 + i4], c = p[2 * WSLAB4 + i4], d = p[3 * WSLAB4 + i4];
    ((float4*)MT)[i4] = make_float4(a.x + b.x + c.x + d.x, a.y + b.y + c.y + d.y,
                                    a.z + b.z + c.z + d.z, a.w + b.w + c.w + d.w);
  }
}

// ---------------------------------------------------------------------------
// D4 k_v: v[b,d] = (1/16) * Q[b,:]·MT[d,:]   grid (24, 32)   (K = 256)
// ---------------------------------------------------------------------------
__global__ void k_v(const float* __restrict__ Qm, const float* __restrict__ MT,
                    float* __restrict__ vv) {
  int d0 = blockIdx.x * 32;
  int b0 = blockIdx.y * 3;
  int lane = threadIdx.x & 63, wave = threadIdx.x >> 6;
  float4 x[3];
#pragma unroll
  for (int bi = 0; bi < 3; ++bi)
    x[bi] = ((const float4*)(Qm + (size_t)(b0 + bi) * AA))[lane];
  for (int i = 0; i < 8; ++i) {
    int d = d0 + wave * 8 + i;
    float4 w = ((const float4*)(MT + (size_t)d * AA))[lane];
    float p[3];
#pragma unroll
    for (int bi = 0; bi < 3; ++bi) p[bi] = dot4(w, x[bi]);
#pragma unroll
    for (int bi = 0; bi < 3; ++bi) {
      float pp = p[bi];
      for (int off = 32; off; off >>= 1) pp += __shfl_down(pp, off, 64);
      if (lane == 0) vv[(size_t)(b0 + bi) * DD + d] = pp * (1.f / 16.f);
    }
  }
}

// ---------------------------------------------------------------------------
// D5 k_scores: scores[b,h] = hist[b,h,:]·v[b,:]   grid (96, 5), 20 h/block
// ---------------------------------------------------------------------------
__global__ void k_scores(const float* __restrict__ hist, const float* __restrict__ vv,
                         float* __restrict__ sc) {
  int b = blockIdx.x, hg = blockIdx.y;
  int lane = threadIdx.x & 63, wave = threadIdx.x >> 6;
  float4 v[3];
  const float4* vb = (const float4*)(vv + (size_t)b * DD);
#pragma unroll
  for (int jj = 0; jj < 3; ++jj) v[jj] = vb[lane + 64 * jj];
  const float* hb = hist + (size_t)b * HH * DD;
  for (int i = 0; i < 5; ++i) {
    int h = hg * 20 + wave * 5 + i;
    const float4* r = (const float4*)(hb + (size_t)h * DD);
    float p = 0.f;
#pragma unroll
    for (int jj = 0; jj < 3; ++jj) p += dot4(r[lane + 64 * jj], v[jj]);
    for (int off = 32; off; off >>= 1) p += __shfl_down(p, off, 64);
    if (lane == 0) sc[b * 128 + h] = p;
  }
}

// ---------------------------------------------------------------------------
// D6 k_wsum: softmax (wave 0, per block) + weighted hist sum.
// HIGH-TLP shape: grid (96, 12), 64 e per block, 4 h-groups x 25 h/thread,
// LDS 4-way reduce. 1152 blocks -> ~18 waves/CU of latency hiding.
// ---------------------------------------------------------------------------
__global__ void __launch_bounds__(256)
k_wsum(const float* __restrict__ hist, const float* __restrict__ sc,
       float* __restrict__ wsum) {
  int b = blockIdx.x;
  int es = blockIdx.y;                 // 64-col slice
  int tid = threadIdx.x, lane = tid & 63, wave = tid >> 6;
  __shared__ float sal[HH];
  __shared__ float psum[4][64];
  if (tid < HH) sal[tid] = sc[b * 128 + tid];
  __syncthreads();
  if (wave == 0) {
    float x0 = (lane < HH) ? sal[lane] : -1e30f;
    float x1 = (lane + 64 < HH) ? sal[lane + 64] : -1e30f;
    float m = fmaxf(x0, x1);
    for (int off = 32; off; off >>= 1) m = fmaxf(m, __shfl_xor(m, off, 64));
    float e0 = (lane < HH) ? __expf(x0 - m) : 0.f;
    float e1 = (lane + 64 < HH) ? __expf(x1 - m) : 0.f;
    float s = e0 + e1;
    for (int off = 32; off; off >>= 1) s += __shfl_xor(s, off, 64);
    float inv = 1.f / s;
    if (lane < HH) sal[lane] = e0 * inv;
    if (lane + 64 < HH) sal[lane + 64] = e1 * inv;
  }
  __syncthreads();
  int e = es * 64 + lane;
  const float* hb = hist + (size_t)b * HH * DD + e;
  int h0 = wave * 25;
  float acc = 0.f;
#pragma unroll
  for (int i = 0; i < 25; i += 5) {  // 5 loads in flight per batch
    float v0 = hb[(size_t)(h0 + i + 0) * DD];
    float v1 = hb[(size_t)(h0 + i + 1) * DD];
    float v2 = hb[(size_t)(h0 + i + 2) * DD];
    float v3 = hb[(size_t)(h0 + i + 3) * DD];
    float v4 = hb[(size_t)(h0 + i + 4) * DD];
    acc += sal[h0 + i + 0] * v0 + sal[h0 + i + 1] * v1 + sal[h0 + i + 2] * v2 +
           sal[h0 + i + 3] * v3 + sal[h0 + i + 4] * v4;
  }
  psum[wave][lane] = acc;
  __syncthreads();
  if (tid < 64) {
    float s = psum[0][tid] + psum[1][tid] + psum[2][tid] + psum[3][tid];
    wsum[(size_t)b * DD + es * 64 + tid] = s;
  }
}

// ---------------------------------------------------------------------------
// D7 k_orow_write: orow[b,d] = nl[b,d] + wsum[b,:]·W_r[d,:], then broadcast
// directly to out[b, 0..127, d] (via LDS stage). grid (24, 32).
// ---------------------------------------------------------------------------
__global__ void k_orow_write(const float* __restrict__ wsum, const float* __restrict__ Wr,
                             const float* __restrict__ nl, float* __restrict__ out) {
  int d0 = blockIdx.x * 32;
  int b0 = blockIdx.y * 3;
  int lane = threadIdx.x & 63, wave = threadIdx.x >> 6;
  __shared__ __align__(16) float s_o[3][32];
  float4 x[3][3];
#pragma unroll
  for (int bi = 0; bi < 3; ++bi)
#pragma unroll
    for (int jj = 0; jj < 3; ++jj)
      x[bi][jj] = ((const float4*)(wsum + (size_t)(b0 + bi) * DD))[lane + 64 * jj];
  for (int i = 0; i < 8; ++i) {
    int d = d0 + wave * 8 + i;
    const float4* w4 = (const float4*)(Wr + (size_t)d * DD);
    float p[3] = {0.f, 0.f, 0.f};
#pragma unroll
    for (int jj = 0; jj < 3; ++jj) {
      float4 w = w4[lane + 64 * jj];
#pragma unroll
      for (int bi = 0; bi < 3; ++bi) p[bi] += dot4(w, x[bi][jj]);
    }
#pragma unroll
    for (int bi = 0; bi < 3; ++bi) {
      float pp = p[bi];
      for (int off = 32; off; off >>= 1) pp += __shfl_down(pp, off, 64);
      if (lane == 0)
        s_o[bi][wave * 8 + i] = pp + nl[(size_t)(b0 + bi) * DD + d];
    }
  }
  __syncthreads();
  float4* out4 = (float4*)out;
  int d4 = d0 >> 2;
#pragma unroll
  for (int k = 0; k < 12; ++k) {
    int g = threadIdx.x + (k << 8);
    int seg = g >> 3, off = g & 7;
    int bi = seg >> 7, n = seg & 127;
    float4 val = *(const float4*)&s_o[bi][off * 4];
    out4[((size_t)(b0 + bi) * NN + n) * (DD / 4) + d4 + off] = val;
  }
}

// ---------------------------------------------------------------------------
extern "C" void kernel_launch(void* const* d_in, const int* in_sizes, int n_in,
                              void* d_out, int out_size, void* d_ws, size_t ws_size,
                              hipStream_t stream) {
  const float *hist = nullptr, *Wl = nullptr, *Wr = nullptr, *WK = nullptr,
              *WQ = nullptr, *bl = nullptr, *bQ = nullptr;
  int seenDxD = 0, seenAxD = 0;
  for (int i = 0; i < n_in; ++i) {
    int s = in_sizes[i];
    const float* p = (const float*)d_in[i];
    if (s == BB * HH * DD) hist = p;
    else if (s == BB * NN * DD) { /* candidate — unused */ }
    else if (s == DD * DD) { if (seenDxD++ == 0) Wl = p; else Wr = p; }
    else if (s == AA * DD) { if (seenAxD++ == 0) WK = p; else WQ = p; }
    else if (s == DD) bl = p;
    else if (s == AA) bQ = p;
  }

  float* ws = (float*)d_ws;
  float* MTp    = ws + 0;         // 4 * 196608 = 786432
  float* MT     = ws + 786432;    // 196608
  float* neighp = ws + 983040;    // 4*96*768 = 294912
  float* nl     = ws + 1277952;   // 73728
  float* u0     = ws + 1351680;   // 73728
  float* Qm     = ws + 1425408;   // 24576
  float* vv     = ws + 1449984;   // 73728
  float* sc     = ws + 1523712;   // 12288
  float* wsum   = ws + 1536000;   // 73728  -> total ~6.4 MB
  float* out = (float*)d_out;

  k_prep      <<<dim3(1152),   dim3(256), 0, stream>>>(Wr, WK, hist, MTp, neighp);
  k_nl_u0     <<<dim3(24, 32), dim3(256), 0, stream>>>(neighp, hist, Wl, bl, Wr, nl, u0);
  k_q         <<<dim3(448),    dim3(256), 0, stream>>>(u0, WQ, bQ, MTp, Qm, MT);
  k_v         <<<dim3(24, 32), dim3(256), 0, stream>>>(Qm, MT, vv);
  k_scores    <<<dim3(96, 5),  dim3(256), 0, stream>>>(hist, vv, sc);
  k_wsum      <<<dim3(96, 12), dim3(256), 0, stream>>>(hist, sc, wsum);
  k_orow_write<<<dim3(24, 32), dim3(256), 0, stream>>>(wsum, Wr, nl, out);
}